// Round 8
// baseline (158.607 us; speedup 1.0000x reference)
//
#include <hip/hip_runtime.h>
#include <hip/hip_bf16.h>

// Dilated-mask attention, B=2 H=16 S=2048 D=64, dilation=2.
// mask[i,j]=1 iff same parity; masked scores exactly 0 -> flash attn over
// same-parity keys with fixed m=0, Z = l + 1024, out += Vsum_otherparity.
//
// R14 = R13 resubmitted verbatim (R13 hit "container failed twice" — infra,
// not kernel: no divergent barriers, legal launch config, bijective decode,
// same launch structure as the passing R11). Design rationale:
// R12 proved the kernel is stall-bound, not pipe-bound (LDS-free variant =
// same 45us; VGPR=124 shows the compiler killed the reg double-buffer).
//  - 128-thread blocks (2 waves x 32 queries, R7-verified dual-qf compute):
//    1024 blocks, 32KB LDS/block -> 5 INDEPENDENT blocks/CU (R7/R12 had 2,
//    R11 had 4) at different phases -> mutual stall filling.
//  - R11-verified preconv bf16 K / V^T staging (linear uint4 copy).
//  - dual-qf halves per-query LDS frag reads vs R11.
//  - bijective XCD swizzle: blocks sharing a bp slice land on one XCD.
//  - s_setprio(1) around MFMA/exp cluster (T5).
// Fallback = fully verified R9 path (ws too small).

#define B_   2
#define H_   16
#define S_   2048
#define D_   64
#define SP_  1024
#define BQ   64         // attn5: 2 waves x 32 queries
#define FBQ  64         // fallback (R9) queries per block
#define BK   64
#define NKT  (SP_ / BK)

// Q pre-scale: 1/sqrt(64) * log2(e)  ->  p = exp2(QK') = exp(QK/8)
#define QSCALE 0.180336884f

#if __has_builtin(__builtin_amdgcn_exp2f)
#define EXP2(x) __builtin_amdgcn_exp2f(x)
#else
#define EXP2(x) exp2f(x)
#endif

typedef __bf16 bf16x8 __attribute__((ext_vector_type(8)));
typedef __bf16 bf16x4 __attribute__((ext_vector_type(4)));
typedef float  f32x4  __attribute__((ext_vector_type(4)));
typedef short  s16x4  __attribute__((ext_vector_type(4)));

static __device__ __forceinline__ f32x4 mfma16(bf16x4 a, bf16x4 b, f32x4 c) {
    return __builtin_amdgcn_mfma_f32_16x16x16bf16_1k(
        __builtin_bit_cast(s16x4, a), __builtin_bit_cast(s16x4, b), c, 0, 0, 0);
}

// XOR-swizzled element offset inside a 64-elem (128 B) row: 16 B chunk c8 of
// row r lands at chunk c8^(r&7).
#define KSW(r, c8) ((((c8) ^ ((r) & 7)) << 3))

// ---------------------------------------------------------------------------
// conv_kernel: VERBATIM R11 (HW-verified). K -> Kbf (bf16, row-swizzled),
// V -> Vt (V^T bf16, swizzled), vsp[bp][kc][d] partial V column sums.
// grid (64 bp, 8 kc), 256 threads.
// ---------------------------------------------------------------------------
__global__ __launch_bounds__(256) void conv_kernel(const float* __restrict__ K,
                                                   const float* __restrict__ V,
                                                   __bf16* __restrict__ Kbf,
                                                   __bf16* __restrict__ Vt,
                                                   float* __restrict__ vsp) {
    const int bp  = blockIdx.x;          // bh*2 + par
    const int kc  = blockIdx.y;          // chunk of 128 parity-local keys
    const int bh  = bp >> 1;
    const int par = bp & 1;
    const int tid = threadIdx.x;
    const float* Kb = K + (size_t)bh * S_ * D_;
    const float* Vb = V + (size_t)bh * S_ * D_;

    // 80-elem rows: 160 B stride -> every row 16 B-aligned (b128-safe).
    __shared__ __align__(16) __bf16 vt[64][80];
    const int row = tid >> 2;            // 0..63 (key row / d row)
    const int c0  = (tid & 3) * 16;      // element offset
    const int c8  = (tid & 3) * 2;       // 8-elem chunk index

    float vsum = 0.f;
    #pragma unroll
    for (int st2 = 0; st2 < 2; ++st2) {
        const int ktile = kc * 2 + st2;  // 0..15
        const int k0 = ktile * 64;
        // ---- K rows: fp32 -> bf16, swizzled chunks (global->global) ----
        {
            const float* ks = Kb + (size_t)(par + 2 * (k0 + row)) * D_ + c0;
            const float4 a0 = *(const float4*)(ks);
            const float4 a1 = *(const float4*)(ks + 4);
            const float4 a2 = *(const float4*)(ks + 8);
            const float4 a3 = *(const float4*)(ks + 12);
            bf16x8 w0, w1;
            w0[0] = (__bf16)a0.x; w0[1] = (__bf16)a0.y;
            w0[2] = (__bf16)a0.z; w0[3] = (__bf16)a0.w;
            w0[4] = (__bf16)a1.x; w0[5] = (__bf16)a1.y;
            w0[6] = (__bf16)a1.z; w0[7] = (__bf16)a1.w;
            w1[0] = (__bf16)a2.x; w1[1] = (__bf16)a2.y;
            w1[2] = (__bf16)a2.z; w1[3] = (__bf16)a2.w;
            w1[4] = (__bf16)a3.x; w1[5] = (__bf16)a3.y;
            w1[6] = (__bf16)a3.z; w1[7] = (__bf16)a3.w;
            __bf16* kdst = Kbf + ((size_t)bp * SP_ + k0 + row) * D_;
            *(bf16x8*)&kdst[KSW(row, c8)]     = w0;
            *(bf16x8*)&kdst[KSW(row, c8 + 1)] = w1;
        }
        // ---- V rows: fp32 -> bf16 into LDS tile [key][d] ----
        {
            const float* vsrc = Vb + (size_t)(par + 2 * (k0 + row)) * D_ + c0;
            const float4 a0 = *(const float4*)(vsrc);
            const float4 a1 = *(const float4*)(vsrc + 4);
            const float4 a2 = *(const float4*)(vsrc + 8);
            const float4 a3 = *(const float4*)(vsrc + 12);
            bf16x8 w0, w1;
            w0[0] = (__bf16)a0.x; w0[1] = (__bf16)a0.y;
            w0[2] = (__bf16)a0.z; w0[3] = (__bf16)a0.w;
            w0[4] = (__bf16)a1.x; w0[5] = (__bf16)a1.y;
            w0[6] = (__bf16)a1.z; w0[7] = (__bf16)a1.w;
            w1[0] = (__bf16)a2.x; w1[1] = (__bf16)a2.y;
            w1[2] = (__bf16)a2.z; w1[3] = (__bf16)a2.w;
            w1[4] = (__bf16)a3.x; w1[5] = (__bf16)a3.y;
            w1[6] = (__bf16)a3.z; w1[7] = (__bf16)a3.w;
            *(bf16x8*)&vt[row][c0]     = w0;
            *(bf16x8*)&vt[row][c0 + 8] = w1;
        }
        __syncthreads();
        // ---- transpose out: Vt[bp][ktile][d][key], swizzled; + vsum ----
        {
            const int d = row;
            #pragma unroll
            for (int cc2 = 0; cc2 < 2; ++cc2) {
                const int cc = c8 + cc2;       // key chunk 0..7
                bf16x8 w;
                float s = 0.f;
                #pragma unroll
                for (int j = 0; j < 8; ++j) {
                    w[j] = vt[cc * 8 + j][d];
                    s += (float)w[j];
                }
                vsum += s;
                __bf16* vdst = Vt + (((size_t)bp * 16 + ktile) * D_ + d) * 64;
                *(bf16x8*)&vdst[KSW(d, cc)] = w;
            }
        }
        __syncthreads();
    }
    // reduce across the 4 threads sharing d; one plain store per (block, d)
    vsum += __shfl_down(vsum, 1);
    vsum += __shfl_down(vsum, 2);
    if ((tid & 3) == 0) vsp[((size_t)bp * 8 + blockIdx.y) * 64 + row] = vsum;
}

// ---------------------------------------------------------------------------
// attn5: 128 threads (2 waves x 32 queries, dual-qf), linear uint4 staging,
// XCD-swizzled grid, setprio around compute. Compute = R7-verified.
// ---------------------------------------------------------------------------
__global__ __launch_bounds__(128, 2) void attn5_kernel(const float* __restrict__ Q,
                                                       const __bf16* __restrict__ Kbf,
                                                       const __bf16* __restrict__ Vt,
                                                       const float* __restrict__ vsp,
                                                       float* __restrict__ out) {
    // Bijective XCD decode (1024 = 8*128): XCD (h&7) serves L in
    // [128*(h&7), ...) -> bh in [4k,4k+4), both parities, all qt -> its 8 bp
    // slices (2 MB of Kbf/Vt) stay in its private L2.
    const int h  = blockIdx.x;
    const int L  = (h & 7) * 128 + (h >> 3);
    const int qt  = L & 15;
    const int par = (L >> 4) & 1;
    const int bh  = L >> 5;
    const int bp  = bh * 2 + par;
    const int tid  = threadIdx.x;
    const int lane = tid & 63;
    const int wave = tid >> 6;       // 2 waves; wave owns queries [32w, 32w+32)
    const int l15  = lane & 15;
    const int quad = lane >> 4;

    // arena: [0,16K) kbuf[2][64][64], [16K,32K) vbuf[2][64][64] (V^T).
    // Epilogue reuses [0,8704) as per-wave f32 transpose tiles [16][68].
    __shared__ __align__(16) char arena[32768];
    __bf16 (*kbuf)[BK][64] = (__bf16 (*)[BK][64])arena;
    __bf16 (*vbuf)[D_][64] = (__bf16 (*)[D_][64])(arena + 16384);

    const size_t base = (size_t)bh * S_ * D_;

    // ---- Q as QK B-operand fragments (st = K·Q^T): B[n=query l15][k=d]
    bf16x8 qf[2][2];                 // [qt2][ks]  (R7-verified)
    #pragma unroll
    for (int qt2 = 0; qt2 < 2; ++qt2) {
        const int qrow = qt * BQ + wave * 32 + qt2 * 16 + l15;
        const float* qsrc = Q + base + (size_t)(par + 2 * qrow) * D_ + quad * 8;
        #pragma unroll
        for (int ks = 0; ks < 2; ++ks) {
            const float4 a = *(const float4*)(qsrc + ks * 32);
            const float4 b = *(const float4*)(qsrc + ks * 32 + 4);
            bf16x8 w;
            w[0] = (__bf16)(a.x * QSCALE); w[1] = (__bf16)(a.y * QSCALE);
            w[2] = (__bf16)(a.z * QSCALE); w[3] = (__bf16)(a.w * QSCALE);
            w[4] = (__bf16)(b.x * QSCALE); w[5] = (__bf16)(b.y * QSCALE);
            w[6] = (__bf16)(b.z * QSCALE); w[7] = (__bf16)(b.w * QSCALE);
            qf[qt2][ks] = w;
        }
    }

    // ---- staging: linear uint4 copy (layout+swizzle pre-baked by conv)
    const uint4* Kt4 = (const uint4*)(Kbf + (size_t)bp * SP_ * D_);
    const uint4* Vt4 = (const uint4*)(Vt  + (size_t)bp * SP_ * D_);
    uint4 sk[4], sv[4];

    auto issue_loads = [&](int kt) {
        #pragma unroll
        for (int i = 0; i < 4; ++i) {
            const int o = kt * 512 + tid + i * 128;   // 512 uint4 per 8 KB tile
            sk[i] = Kt4[o];
            sv[i] = Vt4[o];
        }
    };
    auto stage = [&](int buf) {
        uint4* kd = (uint4*)kbuf[buf];
        uint4* vd = (uint4*)vbuf[buf];
        #pragma unroll
        for (int i = 0; i < 4; ++i) {
            kd[tid + i * 128] = sk[i];
            vd[tid + i * 128] = sv[i];
        }
    };

    issue_loads(0);
    stage(0);
    __syncthreads();

    // O^T accumulators: C[m=d=quad*4+r (+16dt)][n=query=l15], per qt2
    f32x4 acc[2][4];
    #pragma unroll
    for (int q2 = 0; q2 < 2; ++q2)
        #pragma unroll
        for (int dt = 0; dt < 4; ++dt) acc[q2][dt] = (f32x4){0.f, 0.f, 0.f, 0.f};
    float l_acc[2] = {0.f, 0.f};     // per-lane partial Z for query l15 (per qt2)

    for (int kt = 0; kt < NKT; ++kt) {
        const int cur = kt & 1;
        const bool pf = (kt + 1 < NKT);

        if (pf) issue_loads(kt + 1);   // latency overlaps compute below

        const __bf16 (*kb)[64] = kbuf[cur];
        const __bf16 (*vb)[64] = vbuf[cur];

        // ---- K A-fragments for QK (K=32): 8 b128
        bf16x8 ka[2][4];
        #pragma unroll
        for (int ks = 0; ks < 2; ++ks)
            #pragma unroll
            for (int kt4 = 0; kt4 < 4; ++kt4) {
                const int R = kt4 * 16 + l15;
                ka[ks][kt4] = *(const bf16x8*)&kb[R][KSW(R, ks * 4 + quad)];
            }
        // ---- V^T A-fragments for PV (K=16): A[m=d l15][k=key quad*4+j], 16 b64
        bf16x4 va[4][4];             // [kt4][dt]
        #pragma unroll
        for (int dt = 0; dt < 4; ++dt) {
            const int R = dt * 16 + l15;
            const int ro = R & 7;
            #pragma unroll
            for (int kt4 = 0; kt4 < 4; ++kt4) {
                const int ch = (kt4 * 2 + (quad >> 1)) ^ ro;
                va[kt4][dt] = *(const bf16x4*)&vb[R][ch * 8 + (quad & 1) * 4];
            }
        }

        // ---- st = K·Q^T, p = exp2(st) -> P B-frag in regs -> PV directly
        __builtin_amdgcn_s_setprio(1);
        #pragma unroll
        for (int qt2 = 0; qt2 < 2; ++qt2) {
            f32x4 st[4];
            #pragma unroll
            for (int kt4 = 0; kt4 < 4; ++kt4) st[kt4] = (f32x4){0.f, 0.f, 0.f, 0.f};
            #pragma unroll
            for (int ks = 0; ks < 2; ++ks)
                #pragma unroll
                for (int kt4 = 0; kt4 < 4; ++kt4)
                    st[kt4] = __builtin_amdgcn_mfma_f32_16x16x32_bf16(
                        ka[ks][kt4], qf[qt2][ks], st[kt4], 0, 0, 0);
            #pragma unroll
            for (int kt4 = 0; kt4 < 4; ++kt4) {
                const float p0 = EXP2(st[kt4][0]);
                const float p1 = EXP2(st[kt4][1]);
                const float p2 = EXP2(st[kt4][2]);
                const float p3 = EXP2(st[kt4][3]);
                l_acc[qt2] += (p0 + p1) + (p2 + p3);
                bf16x4 pb;
                pb[0] = (__bf16)p0; pb[1] = (__bf16)p1;
                pb[2] = (__bf16)p2; pb[3] = (__bf16)p3;
                #pragma unroll
                for (int dt = 0; dt < 4; ++dt)
                    acc[qt2][dt] = mfma16(va[kt4][dt], pb, acc[qt2][dt]);
            }
        }
        __builtin_amdgcn_s_setprio(0);

        if (pf) stage(1 - cur);
        __syncthreads();
    }

    // ---- epilogue: Z per query (fold quads), opp-parity Vsum from vsp
    float rz[2];
    #pragma unroll
    for (int qt2 = 0; qt2 < 2; ++qt2) {
        float Z = l_acc[qt2];
        Z += __shfl_xor(Z, 16);
        Z += __shfl_xor(Z, 32);
        rz[qt2] = 1.0f / (Z + 1024.0f);
    }
    const float* vsb = vsp + (size_t)(bh * 2 + (1 - par)) * 8 * 64;
    f32x4 vs4[4];
    #pragma unroll
    for (int dt = 0; dt < 4; ++dt) {
        f32x4 s = (f32x4){0.f, 0.f, 0.f, 0.f};
        #pragma unroll
        for (int kc = 0; kc < 8; ++kc)
            s += *(const f32x4*)&vsb[kc * 64 + dt * 16 + quad * 4];
        vs4[dt] = s;
    }

    // ---- epilogue transpose: per-wave private f32 tile [16 q][68 d] in arena
    // (safe: all kbuf/vbuf reads completed before the final barrier)
    float* tw = (float*)arena + wave * (16 * 68);
    #pragma unroll
    for (int qt2 = 0; qt2 < 2; ++qt2) {
        #pragma unroll
        for (int dt = 0; dt < 4; ++dt) {
            const f32x4 o = (acc[qt2][dt] + vs4[dt]) * rz[qt2];
            *(f32x4*)&tw[l15 * 68 + dt * 16 + quad * 4] = o;
        }
        // per-wave private + in-order DS pipe: no barrier needed
        #pragma unroll
        for (int i = 0; i < 4; ++i) {
            const int q = i * 4 + quad;
            const f32x4 ov = *(const f32x4*)&tw[q * 68 + l15 * 4];
            const int qg = par + 2 * (qt * BQ + wave * 32 + qt2 * 16 + q);
            *(f32x4*)&out[base + (size_t)qg * D_ + l15 * 4] = ov;
        }
    }
}

// ---------------------------------------------------------------------------
// Fallback path (verified R9): used only if ws_size is too small.
// ---------------------------------------------------------------------------
__global__ __launch_bounds__(1024) void vsum_kernel(const float* __restrict__ V,
                                                    float* __restrict__ vs) {
    const int bp  = blockIdx.x;
    const int bh  = bp >> 1;
    const int par = bp & 1;
    const int d   = threadIdx.x & 63;
    const int rg  = threadIdx.x >> 6;
    const float* Vb = V + (size_t)bh * S_ * D_;
    float s = 0.f;
    for (int r = rg; r < SP_; r += 16)
        s += Vb[(size_t)(par + 2 * r) * D_ + d];
    __shared__ float red[16][64];
    red[rg][d] = s;
    __syncthreads();
    if (rg == 0) {
        float t = 0.f;
        #pragma unroll
        for (int i = 0; i < 16; ++i) t += red[i][d];
        vs[(size_t)bp * 64 + d] = t;
    }
}

__global__ __launch_bounds__(256, 4) void attn_fb_kernel(const float* __restrict__ Q,
                                                         const float* __restrict__ K,
                                                         const float* __restrict__ V,
                                                         const float* __restrict__ vs,
                                                         float* __restrict__ out) {
    const int bh  = blockIdx.x;
    const int par = blockIdx.y;
    const int qt  = blockIdx.z;
    const int tid  = threadIdx.x;
    const int lane = tid & 63;
    const int wave = tid >> 6;
    const int l15  = lane & 15;
    const int quad = lane >> 4;

    __shared__ __align__(16) char arena[32768];
    __bf16 (*kbuf)[BK][64] = (__bf16 (*)[BK][64])arena;
    __bf16 (*vbuf)[D_][64] = (__bf16 (*)[D_][64])(arena + 16384);

    const size_t base = (size_t)bh * S_ * D_;
    const float* Qb = Q + base;
    const float* Kb = K + base;
    const float* Vb = V + base;

    bf16x8 qf[2];
    {
        const int qrow = qt * FBQ + wave * 16 + l15;
        const float* qsrc = Qb + (size_t)(par + 2 * qrow) * D_ + quad * 8;
        #pragma unroll
        for (int ks = 0; ks < 2; ++ks) {
            const float4 a = *(const float4*)(qsrc + ks * 32);
            const float4 b = *(const float4*)(qsrc + ks * 32 + 4);
            bf16x8 w;
            w[0] = (__bf16)(a.x * QSCALE); w[1] = (__bf16)(a.y * QSCALE);
            w[2] = (__bf16)(a.z * QSCALE); w[3] = (__bf16)(a.w * QSCALE);
            w[4] = (__bf16)(b.x * QSCALE); w[5] = (__bf16)(b.y * QSCALE);
            w[6] = (__bf16)(b.z * QSCALE); w[7] = (__bf16)(b.w * QSCALE);
            qf[ks] = w;
        }
    }

    const int kr0 = tid >> 3;
    const int kc8 = tid & 7;
    float4 pka[2], pkb[2];
    float  pv[16];

    auto issue_loads = [&](int kt) {
        #pragma unroll
        for (int i = 0; i < 2; ++i) {
            const int r = i * 32 + kr0;
            const float* ksrc = Kb + (size_t)(par + 2 * (kt * BK + r)) * D_ + kc8 * 8;
            pka[i] = *(const float4*)ksrc;
            pkb[i] = *(const float4*)(ksrc + 4);
        }
        #pragma unroll
        for (int i = 0; i < 2; ++i) {
            const int c = wave + 4 * i;
            const float* vsrc = Vb + (size_t)(par + 2 * (kt * BK + c * 8)) * D_ + lane;
            #pragma unroll
            for (int j = 0; j < 8; ++j)
                pv[i * 8 + j] = vsrc[(size_t)(2 * j) * D_];
        }
    };
    auto stage = [&](int buf) {
        #pragma unroll
        for (int i = 0; i < 2; ++i) {
            const int r = i * 32 + kr0;
            bf16x8 w;
            w[0] = (__bf16)pka[i].x; w[1] = (__bf16)pka[i].y;
            w[2] = (__bf16)pka[i].z; w[3] = (__bf16)pka[i].w;
            w[4] = (__bf16)pkb[i].x; w[5] = (__bf16)pkb[i].y;
            w[6] = (__bf16)pkb[i].z; w[7] = (__bf16)pkb[i].w;
            *(bf16x8*)&kbuf[buf][r][KSW(r, kc8)] = w;
        }
        #pragma unroll
        for (int i = 0; i < 2; ++i) {
            const int c = wave + 4 * i;
            bf16x8 w;
            #pragma unroll
            for (int j = 0; j < 8; ++j) w[j] = (__bf16)pv[i * 8 + j];
            *(bf16x8*)&vbuf[buf][lane][KSW(lane, c)] = w;
        }
    };

    issue_loads(0);
    stage(0);
    __syncthreads();

    f32x4 acc[4];
    #pragma unroll
    for (int dt = 0; dt < 4; ++dt) acc[dt] = (f32x4){0.f, 0.f, 0.f, 0.f};
    float l_acc = 0.f;

    for (int kt = 0; kt < NKT; ++kt) {
        const int cur = kt & 1;
        const bool pf = (kt + 1 < NKT);
        if (pf) issue_loads(kt + 1);

        const __bf16 (*kb)[64] = kbuf[cur];
        const __bf16 (*vb)[64] = vbuf[cur];

        bf16x8 ka[2][4];
        #pragma unroll
        for (int ks = 0; ks < 2; ++ks)
            #pragma unroll
            for (int kt4 = 0; kt4 < 4; ++kt4) {
                const int R = kt4 * 16 + l15;
                ka[ks][kt4] = *(const bf16x8*)&kb[R][KSW(R, ks * 4 + quad)];
            }
        bf16x4 va[4][4];
        #pragma unroll
        for (int dt = 0; dt < 4; ++dt) {
            const int R = dt * 16 + l15;
            const int ro = R & 7;
            #pragma unroll
            for (int kt4 = 0; kt4 < 4; ++kt4) {
                const int ch = (kt4 * 2 + (quad >> 1)) ^ ro;
                va[kt4][dt] = *(const bf16x4*)&vb[R][ch * 8 + (quad & 1) * 4];
            }
        }

        f32x4 st[4];
        #pragma unroll
        for (int kt4 = 0; kt4 < 4; ++kt4) st[kt4] = (f32x4){0.f, 0.f, 0.f, 0.f};
        #pragma unroll
        for (int ks = 0; ks < 2; ++ks)
            #pragma unroll
            for (int kt4 = 0; kt4 < 4; ++kt4)
                st[kt4] = __builtin_amdgcn_mfma_f32_16x16x32_bf16(
                    ka[ks][kt4], qf[ks], st[kt4], 0, 0, 0);
        #pragma unroll
        for (int kt4 = 0; kt4 < 4; ++kt4) {
            const float p0 = EXP2(st[kt4][0]);
            const float p1 = EXP2(st[kt4][1]);
            const float p2 = EXP2(st[kt4][2]);
            const float p3 = EXP2(st[kt4][3]);
            l_acc += (p0 + p1) + (p2 + p3);
            bf16x4 pb;
            pb[0] = (__bf16)p0; pb[1] = (__bf16)p1;
            pb[2] = (__bf16)p2; pb[3] = (__bf16)p3;
            #pragma unroll
            for (int dt = 0; dt < 4; ++dt)
                acc[dt] = mfma16(va[kt4][dt], pb, acc[dt]);
        }

        if (pf) stage(1 - cur);
        __syncthreads();
    }

    float Z = l_acc;
    Z += __shfl_xor(Z, 16);
    Z += __shfl_xor(Z, 32);
    const float rz = 1.0f / (Z + 1024.0f);
    const float* vso = vs + ((size_t)(bh * 2 + (1 - par))) * 64;

    float* tw = (float*)arena + wave * (16 * 68);
    #pragma unroll
    for (int dt = 0; dt < 4; ++dt) {
        const f32x4 vs4 = *(const f32x4*)&vso[dt * 16 + quad * 4];
        const f32x4 o = (acc[dt] + vs4) * rz;
        *(f32x4*)&tw[l15 * 68 + dt * 16 + quad * 4] = o;
    }
    #pragma unroll
    for (int i = 0; i < 4; ++i) {
        const int q = i * 4 + quad;
        const f32x4 ov = *(const f32x4*)&tw[q * 68 + l15 * 4];
        const int qg = par + 2 * (qt * FBQ + wave * 16 + q);
        *(f32x4*)&out[base + (size_t)qg * D_ + l15 * 4] = ov;
    }
}

extern "C" void kernel_launch(void* const* d_in, const int* in_sizes, int n_in,
                              void* d_out, int out_size, void* d_ws, size_t ws_size,
                              hipStream_t stream) {
    const float* Q = (const float*)d_in[0];
    const float* K = (const float*)d_in[1];
    const float* V = (const float*)d_in[2];
    float* out = (float*)d_out;

    const size_t KBF_BYTES = (size_t)64 * SP_ * D_ * sizeof(__bf16);   // 8 MB
    const size_t VSP_BYTES = (size_t)64 * 8 * 64 * sizeof(float);      // 128 KB
    const size_t need = 2 * KBF_BYTES + VSP_BYTES;

    if (ws_size >= need) {
        __bf16* Kbf = (__bf16*)d_ws;
        __bf16* Vt  = (__bf16*)((char*)d_ws + KBF_BYTES);
        float*  vsp = (float*)((char*)d_ws + 2 * KBF_BYTES);
        conv_kernel<<<dim3(64, 8), dim3(256), 0, stream>>>(K, V, Kbf, Vt, vsp);
        attn5_kernel<<<dim3(64 * 16), dim3(128), 0, stream>>>(
            Q, Kbf, Vt, vsp, out);
    } else {
        float* vsn = (float*)d_ws;     // 16 KB (proven available in R9)
        vsum_kernel<<<dim3(B_ * H_ * 2), dim3(1024), 0, stream>>>(V, vsn);
        attn_fb_kernel<<<dim3(B_ * H_, 2, SP_ / FBQ), dim3(256), 0, stream>>>(
            Q, K, V, vsn, out);
    }
}

// Round 9
// 121.240 us; speedup vs baseline: 1.3082x; 1.3082x over previous
//
#include <hip/hip_runtime.h>
#include <hip/hip_bf16.h>

// Dilated-mask attention, B=2 H=16 S=2048 D=64, dilation=2.
// mask[i,j]=1 iff same parity; masked scores exactly 0 -> flash attn over
// same-parity keys with fixed m=0, Z = l + 1024, out += Vsum_otherparity.
//
// R15: bench = 62us fixed + SUM of dispatch GPU times (refit of R7..R14) ->
// minimize total GPU time; extra dispatches are free.
//  - conv2: one-time K/V -> bf16 in FRAGMENT ORDER (exact per-lane bytes of
//    the R7-verified 16x16 fragments). Reads BOTH parities per block (100%
//    cacheline efficiency, contiguous 128-row spans). V transposed through
//    the R11-proven vt[64][80] LDS tile. vsum partials folded in (bf16).
//  - attn6: dual-qf 32q/wave (R7-verified compute, BQ=128, 256thr, (256,2)
//    no-spill precedent from R12), staging = linear uint4 copy (R11-proven),
//    frag-ordered LDS reads: ka 8x b128 @ lane*16, va 16x b64 @ lane*8 —
//    both streaming conflict-free (kills R11's 4.26M conflict cycles, halves
//    per-query DS). XCD-consistent decode on both kernels.
//  - ws need = 16MB + 128KB = exactly R11's proven-available size.
// Fallback = fully verified R9 path (ws too small).

#define B_   2
#define H_   16
#define S_   2048
#define D_   64
#define SP_  1024
#define BQ   128        // attn6: 4 waves x 32 queries
#define FBQ  64         // fallback (R9) queries per block
#define BK   64
#define NKT  (SP_ / BK)

// Q pre-scale: 1/sqrt(64) * log2(e)  ->  p = exp2(QK') = exp(QK/8)
#define QSCALE 0.180336884f

#if __has_builtin(__builtin_amdgcn_exp2f)
#define EXP2(x) __builtin_amdgcn_exp2f(x)
#else
#define EXP2(x) exp2f(x)
#endif

typedef __bf16 bf16x8 __attribute__((ext_vector_type(8)));
typedef __bf16 bf16x4 __attribute__((ext_vector_type(4)));
typedef float  f32x4  __attribute__((ext_vector_type(4)));
typedef short  s16x4  __attribute__((ext_vector_type(4)));

static __device__ __forceinline__ f32x4 mfma16(bf16x4 a, bf16x4 b, f32x4 c) {
    return __builtin_amdgcn_mfma_f32_16x16x16bf16_1k(
        __builtin_bit_cast(s16x4, a), __builtin_bit_cast(s16x4, b), c, 0, 0, 0);
}

// XOR swizzle: used only by the verified R9 fallback path.
#define KSW(r, c8) ((((c8) ^ ((r) & 7)) << 3))

// ---------------------------------------------------------------------------
// conv2: fragment-ordered one-time conversion, both parities per block.
//  Kf elem ((bp*16+kt)*8 + f)*512 + lane*8 + j  (f = ks*4+kt4) =
//     bf16( K[bh][par + 2*(kt*64 + (f&3)*16 + (lane&15))][((f>>2)*4+(lane>>4))*8 + j] )
//  Vt elem ((bp*16+kt)*16 + g)*256 + lane*4 + j  (g = kt4*4+dt) =
//     bf16( V[bh][par + 2*(kt*64 + kt4*16 + (lane>>4)*4 + j)][dt*16 + (lane&15)] )
//  vsp[(bp*16+kt)*64 + d] = bf16( sum over tile's 64 keys of f32(bf16(V[..][d])) )
// grid 512 = 8 xcd * 4 bh_local * 16 kt, 256 threads.
// ---------------------------------------------------------------------------
__global__ __launch_bounds__(256) void conv2_kernel(const float* __restrict__ K,
                                                    const float* __restrict__ V,
                                                    __bf16* __restrict__ Kf,
                                                    __bf16* __restrict__ Vt,
                                                    __bf16* __restrict__ vsp) {
    const int id  = blockIdx.x;
    const int l2  = id >> 3;
    const int bh  = (id & 7) * 4 + (l2 & 3);
    const int kt  = l2 >> 2;                 // 0..15
    const int tid = threadIdx.x;
    const float* Kb = K + (size_t)bh * S_ * D_;
    const float* Vb = V + (size_t)bh * S_ * D_;

    // ---- K fragments: 1024 tuples (par, f, lane), 4 per thread ----
    #pragma unroll
    for (int i = 0; i < 4; ++i) {
        const int u    = tid + 256 * i;
        const int par  = u >> 9;
        const int f    = (u >> 6) & 7;
        const int lane = u & 63;
        const int key  = kt * 64 + (f & 3) * 16 + (lane & 15);
        const int col  = ((f >> 2) * 4 + (lane >> 4)) * 8;
        const float* src = Kb + (size_t)(par + 2 * key) * D_ + col;
        const float4 a = *(const float4*)src;
        const float4 b = *(const float4*)(src + 4);
        bf16x8 w;
        w[0] = (__bf16)a.x; w[1] = (__bf16)a.y;
        w[2] = (__bf16)a.z; w[3] = (__bf16)a.w;
        w[4] = (__bf16)b.x; w[5] = (__bf16)b.y;
        w[6] = (__bf16)b.z; w[7] = (__bf16)b.w;
        const size_t bp = (size_t)(bh * 2 + par);
        *(bf16x8*)&Kf[((bp * NKT + kt) * 8 + f) * 512 + lane * 8] = w;
    }

    // ---- V: per parity, transpose through LDS tile (R11-proven pattern) ----
    __shared__ __align__(16) __bf16 vt[64][80];   // 160 B rows: b128-safe
    const int row = tid >> 2;            // 0..63
    const int c0  = (tid & 3) * 16;

    #pragma unroll
    for (int par = 0; par < 2; ++par) {
        // load + cvt: V rows -> vt[key][d]
        {
            const float* vsrc = Vb + (size_t)(par + 2 * (kt * 64 + row)) * D_ + c0;
            const float4 a0 = *(const float4*)(vsrc);
            const float4 a1 = *(const float4*)(vsrc + 4);
            const float4 a2 = *(const float4*)(vsrc + 8);
            const float4 a3 = *(const float4*)(vsrc + 12);
            bf16x8 w0, w1;
            w0[0] = (__bf16)a0.x; w0[1] = (__bf16)a0.y;
            w0[2] = (__bf16)a0.z; w0[3] = (__bf16)a0.w;
            w0[4] = (__bf16)a1.x; w0[5] = (__bf16)a1.y;
            w0[6] = (__bf16)a1.z; w0[7] = (__bf16)a1.w;
            w1[0] = (__bf16)a2.x; w1[1] = (__bf16)a2.y;
            w1[2] = (__bf16)a2.z; w1[3] = (__bf16)a2.w;
            w1[4] = (__bf16)a3.x; w1[5] = (__bf16)a3.y;
            w1[6] = (__bf16)a3.z; w1[7] = (__bf16)a3.w;
            *(bf16x8*)&vt[row][c0]     = w0;
            *(bf16x8*)&vt[row][c0 + 8] = w1;
        }
        __syncthreads();
        // transpose out in fragment order + vsum
        {
            const int d   = row;                 // 0..63
            const int dt  = d >> 4;
            const int l15 = d & 15;
            const size_t bp = (size_t)(bh * 2 + par);
            const size_t tb = (bp * NKT + kt) * 16;   // g-tile base (x256 elems)
            float vsum = 0.f;
            #pragma unroll
            for (int cc2 = 0; cc2 < 2; ++cc2) {
                const int cc  = (tid & 3) * 2 + cc2;  // key chunk 0..7
                const int kt4 = cc >> 1;
                const int qa  = (cc & 1) * 2;         // reader quad of keys m=0..3
                bf16x4 wa, wb;
                #pragma unroll
                for (int m = 0; m < 4; ++m) {
                    const __bf16 x = vt[cc * 8 + m][d];
                    const __bf16 y = vt[cc * 8 + 4 + m][d];
                    wa[m] = x; wb[m] = y;
                    vsum += (float)x + (float)y;
                }
                const int g = kt4 * 4 + dt;
                *(bf16x4*)&Vt[(tb + g) * 256 + (qa * 16 + l15) * 4]       = wa;
                *(bf16x4*)&Vt[(tb + g) * 256 + ((qa + 1) * 16 + l15) * 4] = wb;
            }
            // reduce the 4 threads sharing d (lanes t..t+3, same wave)
            vsum += __shfl_down(vsum, 1);
            vsum += __shfl_down(vsum, 2);
            if ((tid & 3) == 0)
                vsp[(bp * NKT + kt) * 64 + d] = (__bf16)vsum;
        }
        __syncthreads();
    }
}

// ---------------------------------------------------------------------------
// attn6: dual-qf 32q/wave, linear uint4 staging, frag-ordered conflict-free
// LDS reads. Compute = R7-verified.
// ---------------------------------------------------------------------------
__global__ __launch_bounds__(256, 2) void attn6_kernel(const float* __restrict__ Q,
                                                       const __bf16* __restrict__ Kf,
                                                       const __bf16* __restrict__ Vt,
                                                       const __bf16* __restrict__ vsp,
                                                       float* __restrict__ out) {
    // XCD-consistent decode: same bh-grouping as conv2 (id&7 selects group).
    const int id  = blockIdx.x;
    const int l2  = id >> 3;
    const int bh  = (id & 7) * 4 + (l2 & 3);
    const int par = (l2 >> 2) & 1;
    const int qt  = l2 >> 3;                 // 0..7
    const int bp  = bh * 2 + par;
    const int tid  = threadIdx.x;
    const int lane = tid & 63;
    const int wave = tid >> 6;       // wave owns queries [32w, 32w+32)
    const int l15  = lane & 15;
    const int quad = lane >> 4;

    // arena: kbuf[2] at 0,8192; vbuf[2] at 16384,24576 (8 KB frag-tiles).
    // Epilogue reuses [0,17408) as per-wave f32 transpose tiles [16][68].
    __shared__ __align__(16) char arena[32768];

    const size_t base = (size_t)bh * S_ * D_;

    // ---- Q as QK B-operand fragments (st = K·Q^T): B[n=query l15][k=d]
    bf16x8 qf[2][2];                 // [qt2][ks]  (R7-verified)
    #pragma unroll
    for (int qt2 = 0; qt2 < 2; ++qt2) {
        const int qrow = qt * BQ + wave * 32 + qt2 * 16 + l15;
        const float* qsrc = Q + base + (size_t)(par + 2 * qrow) * D_ + quad * 8;
        #pragma unroll
        for (int ks = 0; ks < 2; ++ks) {
            const float4 a = *(const float4*)(qsrc + ks * 32);
            const float4 b = *(const float4*)(qsrc + ks * 32 + 4);
            bf16x8 w;
            w[0] = (__bf16)(a.x * QSCALE); w[1] = (__bf16)(a.y * QSCALE);
            w[2] = (__bf16)(a.z * QSCALE); w[3] = (__bf16)(a.w * QSCALE);
            w[4] = (__bf16)(b.x * QSCALE); w[5] = (__bf16)(b.y * QSCALE);
            w[6] = (__bf16)(b.z * QSCALE); w[7] = (__bf16)(b.w * QSCALE);
            qf[qt2][ks] = w;
        }
    }

    // ---- staging: linear uint4 copy of 8 KB K-tile + 8 KB V-tile
    const uint4* Kt4 = (const uint4*)(Kf + (size_t)bp * NKT * 4096);
    const uint4* Vt4 = (const uint4*)(Vt + (size_t)bp * NKT * 4096);
    uint4 sk0, sk1, sv0, sv1;

    auto issue_loads = [&](int kt) {
        const int o = kt * 512 + tid;
        sk0 = Kt4[o]; sk1 = Kt4[o + 256];
        sv0 = Vt4[o]; sv1 = Vt4[o + 256];
    };
    auto stage = [&](int buf) {
        uint4* kd = (uint4*)(arena + buf * 8192);
        uint4* vd = (uint4*)(arena + 16384 + buf * 8192);
        kd[tid] = sk0; kd[tid + 256] = sk1;
        vd[tid] = sv0; vd[tid + 256] = sv1;
    };

    issue_loads(0);
    stage(0);
    __syncthreads();

    // O^T accumulators: C[m=d=quad*4+r (+16dt)][n=query=l15], per qt2
    f32x4 acc[2][4];
    #pragma unroll
    for (int q2 = 0; q2 < 2; ++q2)
        #pragma unroll
        for (int dt = 0; dt < 4; ++dt) acc[q2][dt] = (f32x4){0.f, 0.f, 0.f, 0.f};
    float l_acc[2] = {0.f, 0.f};     // per-lane partial Z for query l15 (per qt2)

    for (int kt = 0; kt < NKT; ++kt) {
        const int cur = kt & 1;
        const bool pf = (kt + 1 < NKT);

        if (pf) issue_loads(kt + 1);   // latency overlaps compute below

        const char* kb = arena + cur * 8192;
        const char* vb = arena + 16384 + cur * 8192;

        // ---- K A-fragments (QK): 8 streaming b128 (conflict-free)
        bf16x8 ka[2][4];
        #pragma unroll
        for (int ks = 0; ks < 2; ++ks)
            #pragma unroll
            for (int kt4 = 0; kt4 < 4; ++kt4)
                ka[ks][kt4] = *(const bf16x8*)(kb + (ks * 4 + kt4) * 1024 + lane * 16);
        // ---- V^T A-fragments (PV): 16 streaming b64 (conflict-free)
        bf16x4 va[4][4];             // [kt4][dt]
        #pragma unroll
        for (int kt4 = 0; kt4 < 4; ++kt4)
            #pragma unroll
            for (int dt = 0; dt < 4; ++dt)
                va[kt4][dt] = *(const bf16x4*)(vb + (kt4 * 4 + dt) * 512 + lane * 8);

        // ---- st = K·Q^T, p = exp2(st) -> P B-frag in regs -> PV directly
        #pragma unroll
        for (int qt2 = 0; qt2 < 2; ++qt2) {
            f32x4 st[4];
            #pragma unroll
            for (int kt4 = 0; kt4 < 4; ++kt4) st[kt4] = (f32x4){0.f, 0.f, 0.f, 0.f};
            #pragma unroll
            for (int ks = 0; ks < 2; ++ks)
                #pragma unroll
                for (int kt4 = 0; kt4 < 4; ++kt4)
                    st[kt4] = __builtin_amdgcn_mfma_f32_16x16x32_bf16(
                        ka[ks][kt4], qf[qt2][ks], st[kt4], 0, 0, 0);
            #pragma unroll
            for (int kt4 = 0; kt4 < 4; ++kt4) {
                const float p0 = EXP2(st[kt4][0]);
                const float p1 = EXP2(st[kt4][1]);
                const float p2 = EXP2(st[kt4][2]);
                const float p3 = EXP2(st[kt4][3]);
                l_acc[qt2] += (p0 + p1) + (p2 + p3);
                bf16x4 pb;
                pb[0] = (__bf16)p0; pb[1] = (__bf16)p1;
                pb[2] = (__bf16)p2; pb[3] = (__bf16)p3;
                #pragma unroll
                for (int dt = 0; dt < 4; ++dt)
                    acc[qt2][dt] = mfma16(va[kt4][dt], pb, acc[qt2][dt]);
            }
        }

        if (pf) stage(1 - cur);
        __syncthreads();
    }

    // ---- epilogue: Z per query (fold quads), opp-parity Vsum from vsp
    float rz[2];
    #pragma unroll
    for (int qt2 = 0; qt2 < 2; ++qt2) {
        float Z = l_acc[qt2];
        Z += __shfl_xor(Z, 16);
        Z += __shfl_xor(Z, 32);
        rz[qt2] = 1.0f / (Z + 1024.0f);
    }
    const __bf16* vsb = vsp + (size_t)(bh * 2 + (1 - par)) * NKT * 64;
    f32x4 vs4[4];
    #pragma unroll
    for (int dt = 0; dt < 4; ++dt) {
        f32x4 s = (f32x4){0.f, 0.f, 0.f, 0.f};
        #pragma unroll
        for (int kt = 0; kt < NKT; ++kt) {
            const bf16x4 v = *(const bf16x4*)&vsb[kt * 64 + dt * 16 + quad * 4];
            s[0] += (float)v[0]; s[1] += (float)v[1];
            s[2] += (float)v[2]; s[3] += (float)v[3];
        }
        vs4[dt] = s;
    }

    // ---- epilogue transpose: per-wave private f32 tile [16 q][68 d] in arena
    // (safe: all kbuf/vbuf reads completed before the final barrier)
    float* tw = (float*)arena + wave * (16 * 68);
    #pragma unroll
    for (int qt2 = 0; qt2 < 2; ++qt2) {
        #pragma unroll
        for (int dt = 0; dt < 4; ++dt) {
            const f32x4 o = (acc[qt2][dt] + vs4[dt]) * rz[qt2];
            *(f32x4*)&tw[l15 * 68 + dt * 16 + quad * 4] = o;
        }
        // per-wave private + in-order DS pipe: no barrier needed
        #pragma unroll
        for (int i = 0; i < 4; ++i) {
            const int q = i * 4 + quad;
            const f32x4 ov = *(const f32x4*)&tw[q * 68 + l15 * 4];
            const int qg = par + 2 * (qt * BQ + wave * 32 + qt2 * 16 + q);
            *(f32x4*)&out[base + (size_t)qg * D_ + l15 * 4] = ov;
        }
    }
}

// ---------------------------------------------------------------------------
// Fallback path (verified R9): used only if ws_size is too small.
// ---------------------------------------------------------------------------
__global__ __launch_bounds__(1024) void vsum_kernel(const float* __restrict__ V,
                                                    float* __restrict__ vs) {
    const int bp  = blockIdx.x;
    const int bh  = bp >> 1;
    const int par = bp & 1;
    const int d   = threadIdx.x & 63;
    const int rg  = threadIdx.x >> 6;
    const float* Vb = V + (size_t)bh * S_ * D_;
    float s = 0.f;
    for (int r = rg; r < SP_; r += 16)
        s += Vb[(size_t)(par + 2 * r) * D_ + d];
    __shared__ float red[16][64];
    red[rg][d] = s;
    __syncthreads();
    if (rg == 0) {
        float t = 0.f;
        #pragma unroll
        for (int i = 0; i < 16; ++i) t += red[i][d];
        vs[(size_t)bp * 64 + d] = t;
    }
}

__global__ __launch_bounds__(256, 4) void attn_fb_kernel(const float* __restrict__ Q,
                                                         const float* __restrict__ K,
                                                         const float* __restrict__ V,
                                                         const float* __restrict__ vs,
                                                         float* __restrict__ out) {
    const int bh  = blockIdx.x;
    const int par = blockIdx.y;
    const int qt  = blockIdx.z;
    const int tid  = threadIdx.x;
    const int lane = tid & 63;
    const int wave = tid >> 6;
    const int l15  = lane & 15;
    const int quad = lane >> 4;

    __shared__ __align__(16) char arena[32768];
    __bf16 (*kbuf)[BK][64] = (__bf16 (*)[BK][64])arena;
    __bf16 (*vbuf)[D_][64] = (__bf16 (*)[D_][64])(arena + 16384);

    const size_t base = (size_t)bh * S_ * D_;
    const float* Qb = Q + base;
    const float* Kb = K + base;
    const float* Vb = V + base;

    bf16x8 qf[2];
    {
        const int qrow = qt * FBQ + wave * 16 + l15;
        const float* qsrc = Qb + (size_t)(par + 2 * qrow) * D_ + quad * 8;
        #pragma unroll
        for (int ks = 0; ks < 2; ++ks) {
            const float4 a = *(const float4*)(qsrc + ks * 32);
            const float4 b = *(const float4*)(qsrc + ks * 32 + 4);
            bf16x8 w;
            w[0] = (__bf16)(a.x * QSCALE); w[1] = (__bf16)(a.y * QSCALE);
            w[2] = (__bf16)(a.z * QSCALE); w[3] = (__bf16)(a.w * QSCALE);
            w[4] = (__bf16)(b.x * QSCALE); w[5] = (__bf16)(b.y * QSCALE);
            w[6] = (__bf16)(b.z * QSCALE); w[7] = (__bf16)(b.w * QSCALE);
            qf[ks] = w;
        }
    }

    const int kr0 = tid >> 3;
    const int kc8 = tid & 7;
    float4 pka[2], pkb[2];
    float  pv[16];

    auto issue_loads = [&](int kt) {
        #pragma unroll
        for (int i = 0; i < 2; ++i) {
            const int r = i * 32 + kr0;
            const float* ksrc = Kb + (size_t)(par + 2 * (kt * BK + r)) * D_ + kc8 * 8;
            pka[i] = *(const float4*)ksrc;
            pkb[i] = *(const float4*)(ksrc + 4);
        }
        #pragma unroll
        for (int i = 0; i < 2; ++i) {
            const int c = wave + 4 * i;
            const float* vsrc = Vb + (size_t)(par + 2 * (kt * BK + c * 8)) * D_ + lane;
            #pragma unroll
            for (int j = 0; j < 8; ++j)
                pv[i * 8 + j] = vsrc[(size_t)(2 * j) * D_];
        }
    };
    auto stage = [&](int buf) {
        #pragma unroll
        for (int i = 0; i < 2; ++i) {
            const int r = i * 32 + kr0;
            bf16x8 w;
            w[0] = (__bf16)pka[i].x; w[1] = (__bf16)pka[i].y;
            w[2] = (__bf16)pka[i].z; w[3] = (__bf16)pka[i].w;
            w[4] = (__bf16)pkb[i].x; w[5] = (__bf16)pkb[i].y;
            w[6] = (__bf16)pkb[i].z; w[7] = (__bf16)pkb[i].w;
            *(bf16x8*)&kbuf[buf][r][KSW(r, kc8)] = w;
        }
        #pragma unroll
        for (int i = 0; i < 2; ++i) {
            const int c = wave + 4 * i;
            bf16x8 w;
            #pragma unroll
            for (int j = 0; j < 8; ++j) w[j] = (__bf16)pv[i * 8 + j];
            *(bf16x8*)&vbuf[buf][lane][KSW(lane, c)] = w;
        }
    };

    issue_loads(0);
    stage(0);
    __syncthreads();

    f32x4 acc[4];
    #pragma unroll
    for (int dt = 0; dt < 4; ++dt) acc[dt] = (f32x4){0.f, 0.f, 0.f, 0.f};
    float l_acc = 0.f;

    for (int kt = 0; kt < NKT; ++kt) {
        const int cur = kt & 1;
        const bool pf = (kt + 1 < NKT);
        if (pf) issue_loads(kt + 1);

        const __bf16 (*kb)[64] = kbuf[cur];
        const __bf16 (*vb)[64] = vbuf[cur];

        bf16x8 ka[2][4];
        #pragma unroll
        for (int ks = 0; ks < 2; ++ks)
            #pragma unroll
            for (int kt4 = 0; kt4 < 4; ++kt4) {
                const int R = kt4 * 16 + l15;
                ka[ks][kt4] = *(const bf16x8*)&kb[R][KSW(R, ks * 4 + quad)];
            }
        bf16x4 va[4][4];
        #pragma unroll
        for (int dt = 0; dt < 4; ++dt) {
            const int R = dt * 16 + l15;
            const int ro = R & 7;
            #pragma unroll
            for (int kt4 = 0; kt4 < 4; ++kt4) {
                const int ch = (kt4 * 2 + (quad >> 1)) ^ ro;
                va[kt4][dt] = *(const bf16x4*)&vb[R][ch * 8 + (quad & 1) * 4];
            }
        }

        f32x4 st[4];
        #pragma unroll
        for (int kt4 = 0; kt4 < 4; ++kt4) st[kt4] = (f32x4){0.f, 0.f, 0.f, 0.f};
        #pragma unroll
        for (int ks = 0; ks < 2; ++ks)
            #pragma unroll
            for (int kt4 = 0; kt4 < 4; ++kt4)
                st[kt4] = __builtin_amdgcn_mfma_f32_16x16x32_bf16(
                    ka[ks][kt4], qf[ks], st[kt4], 0, 0, 0);
        #pragma unroll
        for (int kt4 = 0; kt4 < 4; ++kt4) {
            const float p0 = EXP2(st[kt4][0]);
            const float p1 = EXP2(st[kt4][1]);
            const float p2 = EXP2(st[kt4][2]);
            const float p3 = EXP2(st[kt4][3]);
            l_acc += (p0 + p1) + (p2 + p3);
            bf16x4 pb;
            pb[0] = (__bf16)p0; pb[1] = (__bf16)p1;
            pb[2] = (__bf16)p2; pb[3] = (__bf16)p3;
            #pragma unroll
            for (int dt = 0; dt < 4; ++dt)
                acc[dt] = mfma16(va[kt4][dt], pb, acc[dt]);
        }

        if (pf) stage(1 - cur);
        __syncthreads();
    }

    float Z = l_acc;
    Z += __shfl_xor(Z, 16);
    Z += __shfl_xor(Z, 32);
    const float rz = 1.0f / (Z + 1024.0f);
    const float* vso = vs + ((size_t)(bh * 2 + (1 - par))) * 64;

    float* tw = (float*)arena + wave * (16 * 68);
    #pragma unroll
    for (int dt = 0; dt < 4; ++dt) {
        const f32x4 vs4 = *(const f32x4*)&vso[dt * 16 + quad * 4];
        const f32x4 o = (acc[dt] + vs4) * rz;
        *(f32x4*)&tw[l15 * 68 + dt * 16 + quad * 4] = o;
    }
    #pragma unroll
    for (int i = 0; i < 4; ++i) {
        const int q = i * 4 + quad;
        const f32x4 ov = *(const f32x4*)&tw[q * 68 + l15 * 4];
        const int qg = par + 2 * (qt * FBQ + wave * 16 + q);
        *(f32x4*)&out[base + (size_t)qg * D_ + l15 * 4] = ov;
    }
}

extern "C" void kernel_launch(void* const* d_in, const int* in_sizes, int n_in,
                              void* d_out, int out_size, void* d_ws, size_t ws_size,
                              hipStream_t stream) {
    const float* Q = (const float*)d_in[0];
    const float* K = (const float*)d_in[1];
    const float* V = (const float*)d_in[2];
    float* out = (float*)d_out;

    const size_t KF_BYTES  = (size_t)64 * NKT * 4096 * sizeof(__bf16);  // 8 MB
    const size_t VT_BYTES  = (size_t)64 * NKT * 4096 * sizeof(__bf16);  // 8 MB
    const size_t VSP_BYTES = (size_t)64 * NKT * 64 * sizeof(__bf16);    // 128 KB
    const size_t need = KF_BYTES + VT_BYTES + VSP_BYTES;   // == R11's proven need

    if (ws_size >= need) {
        __bf16* Kf  = (__bf16*)d_ws;
        __bf16* Vt  = (__bf16*)((char*)d_ws + KF_BYTES);
        __bf16* vsp = (__bf16*)((char*)d_ws + KF_BYTES + VT_BYTES);
        conv2_kernel<<<dim3(512), dim3(256), 0, stream>>>(K, V, Kf, Vt, vsp);
        attn6_kernel<<<dim3(512), dim3(256), 0, stream>>>(Q, Kf, Vt, vsp, out);
    } else {
        float* vsn = (float*)d_ws;     // 16 KB (proven available in R9)
        vsum_kernel<<<dim3(B_ * H_ * 2), dim3(1024), 0, stream>>>(V, vsn);
        attn_fb_kernel<<<dim3(B_ * H_, 2, SP_ / FBQ), dim3(256), 0, stream>>>(
            Q, K, V, vsn, out);
    }
}